// Round 12
// baseline (227.299 us; speedup 1.0000x reference)
//
#include <hip/hip_runtime.h>

#define F 128

typedef __attribute__((ext_vector_type(8))) __bf16 bf16x8;
typedef __attribute__((ext_vector_type(4))) float f32x4;

__device__ __forceinline__ float bflo(unsigned u) { return __uint_as_float(u << 16); }
__device__ __forceinline__ float bfhi(unsigned u) { return __uint_as_float(u & 0xffff0000u); }
__device__ __forceinline__ unsigned short bfbits(float f) {
  __bf16 h = (__bf16)f;
  union { __bf16 b; unsigned short s; } v; v.b = h; return v.s;
}
__device__ __forceinline__ unsigned packbf(float a, float b) {
  return (unsigned)bfbits(a) | ((unsigned)bfbits(b) << 16);
}

__device__ __forceinline__ bf16x8 load_frag_f32(const float* __restrict__ A, int row, int off) {
  const float* a = A + (size_t)row * F + off;
  float4 u = *(const float4*)a, v = *(const float4*)(a + 4);
  bf16x8 r;
  r[0] = (__bf16)u.x; r[1] = (__bf16)u.y; r[2] = (__bf16)u.z; r[3] = (__bf16)u.w;
  r[4] = (__bf16)v.x; r[5] = (__bf16)v.y; r[6] = (__bf16)v.z; r[7] = (__bf16)v.w;
  return r;
}

__device__ __forceinline__ void pack_body(const float* __restrict__ W,
                                          unsigned short* __restrict__ Wp, int idx) {
  int l = idx & 63, ct = idx >> 6, t = ct & 3, c = ct >> 2;
  int q = l >> 4, m = l & 15;
  #pragma unroll
  for (int j = 0; j < 8; ++j)
    Wp[idx * 8 + j] = bfbits(W[(t * 32 + q * 8 + j) * F + c * 16 + m]);
}

// ========== K_A: layer-1 GEMM (own W1 LDS-pack) ∪ histogram+slots ∪ Wp2 pack ==========
// gemm1 depends only on inputs x/W1 -> overlaps the 600k-atomic histogram.
// H1 written UNSCALED (dis not folded; weights live in csr entries instead).
__global__ __launch_bounds__(256) void k_gemm1_count_pack(
    const float* __restrict__ x, const float* __restrict__ W1,
    const int* __restrict__ dst, int* __restrict__ deg, int* __restrict__ slot,
    int E, int gb, int cb,
    const float* __restrict__ W2, unsigned short* __restrict__ Wp2,
    unsigned short* __restrict__ H1, int nTiles, int N) {
  __shared__ unsigned short wlds[2048 * 8];   // 32 KB packed W1 fragments
  int b = blockIdx.x;
  int tid = threadIdx.x;
  if (b < gb) {
    for (int f = tid; f < 2048; f += 256) {
      int l = f & 63, ct = f >> 6, t = ct & 3, c = ct >> 2;
      int q = l >> 4, m = l & 15;
      #pragma unroll
      for (int j = 0; j < 8; ++j)
        wlds[f * 8 + j] = bfbits(W1[(t * 32 + q * 8 + j) * F + c * 16 + m]);
    }
    __syncthreads();
    int gid = b * 4 + (tid >> 6);
    if (gid >= nTiles) return;
    int lane = tid & 63, m = lane & 15, q = lane >> 4;
    const int row0 = gid * 32;
    const bool has2 = (row0 + 16) < N;
    f32x4 acc[2][8];
    #pragma unroll
    for (int h = 0; h < 2; ++h)
      #pragma unroll
      for (int c = 0; c < 8; ++c) acc[h][c] = (f32x4){0.f, 0.f, 0.f, 0.f};
    const int r0 = row0 + m, r1 = row0 + 16 + m;
    #pragma unroll 1
    for (int t = 0; t < 4; ++t) {
      bf16x8 a0 = load_frag_f32(x, r0, q * 8 + t * 32);
      bf16x8 a1 = has2 ? load_frag_f32(x, r1, q * 8 + t * 32) : a0;
      #pragma unroll
      for (int c = 0; c < 8; ++c) {
        bf16x8 w = *(const bf16x8*)(wlds + ((size_t)(c * 4 + t) * 64 + lane) * 8);
        acc[0][c] = __builtin_amdgcn_mfma_f32_16x16x32_bf16(a0, w, acc[0][c], 0, 0, 0);
        acc[1][c] = __builtin_amdgcn_mfma_f32_16x16x32_bf16(a1, w, acc[1][c], 0, 0, 0);
      }
    }
    #pragma unroll
    for (int c = 0; c < 8; ++c)
      #pragma unroll
      for (int r = 0; r < 4; ++r)
        H1[(size_t)(row0 + q * 4 + r) * F + c * 16 + m] = bfbits(acc[0][c][r]);
    if (has2) {
      #pragma unroll
      for (int c = 0; c < 8; ++c)
        #pragma unroll
        for (int r = 0; r < 4; ++r)
          H1[(size_t)(row0 + 16 + q * 4 + r) * F + c * 16 + m] = bfbits(acc[1][c][r]);
    }
  } else if (b < gb + cb) {
    int base = ((b - gb) * 256 + tid) * 4;
    if (base + 3 < E) {
      int4 d = *(const int4*)(dst + base);
      int s0 = atomicAdd(&deg[d.x], 1);
      int s1 = atomicAdd(&deg[d.y], 1);
      int s2 = atomicAdd(&deg[d.z], 1);
      int s3 = atomicAdd(&deg[d.w], 1);
      *(int4*)(slot + base) = make_int4(s0, s1, s2, s3);
    } else {
      for (int k = base; k < E; ++k) slot[k] = atomicAdd(&deg[dst[k]], 1);
    }
  } else {
    pack_body(W2, Wp2, (b - gb - cb) * 256 + tid);
  }
}

// ========== decoupled-lookback scan (+ dis = rsqrt(deg+1)) ==========
__global__ __launch_bounds__(256) void k_scan(const int* __restrict__ deg,
                                              int* __restrict__ row_ptr,
                                              float* __restrict__ dis,
                                              unsigned long long* __restrict__ status,
                                              int* __restrict__ dyn_ctr, int N) {
  __shared__ int s_bid;
  if (threadIdx.x == 0) s_bid = atomicAdd(dyn_ctr, 1);
  __syncthreads();
  const int bid = s_bid;
  int i = bid * 256 + threadIdx.x;
  int lane = threadIdx.x & 63, wid = threadIdx.x >> 6;
  int d = (i < N) ? deg[i] : 0;
  if (i < N) dis[i] = rsqrtf((float)d + 1.0f);
  int v = d;
  #pragma unroll
  for (int o = 1; o < 64; o <<= 1) {
    int t = __shfl_up(v, o);
    if (lane >= o) v += t;
  }
  __shared__ int wsum[4];
  __shared__ int s_excl;
  if (lane == 63) wsum[wid] = v;
  __syncthreads();
  if (threadIdx.x == 0) {
    int run = 0;
    #pragma unroll
    for (int w = 0; w < 4; ++w) { run += wsum[w]; wsum[w] = run; }
    int total = run;
    unsigned long long st = ((unsigned long long)(bid == 0 ? 2 : 1) << 32) |
                            (unsigned long long)(unsigned)total;
    atomicExch(&status[bid], st);
    int excl = 0;
    if (bid > 0) {
      int j = bid - 1;
      while (true) {
        unsigned long long s = atomicAdd(&status[j], 0ULL);
        unsigned flag = (unsigned)(s >> 32);
        if (flag == 0) { __builtin_amdgcn_s_sleep(1); continue; }
        excl += (int)(unsigned)s;
        if (flag == 2) break;
        --j;
      }
      atomicExch(&status[bid], (2ULL << 32) | (unsigned long long)(unsigned)(excl + total));
    }
    s_excl = excl;
  }
  __syncthreads();
  int excl = s_excl;
  if (wid > 0) v += wsum[wid - 1];
  if (i < N) row_ptr[i + 1] = excl + v;
  if (i == 0) row_ptr[0] = 0;
}

// ========== atomic-free CSR fill: csr[rp[d]+slot] = (src, dis[src]) ==========
__global__ __launch_bounds__(256) void k_fill(const int* __restrict__ src,
                                              const int* __restrict__ dst,
                                              const int* __restrict__ slot,
                                              const int* __restrict__ rp,
                                              const float* __restrict__ dis,
                                              int2* __restrict__ csr, int E) {
  int base = (blockIdx.x * 256 + threadIdx.x) * 4;
  if (base + 3 < E) {
    int4 s = *(const int4*)(src + base);
    int4 d = *(const int4*)(dst + base);
    int4 sl = *(const int4*)(slot + base);
    csr[rp[d.x] + sl.x] = make_int2(s.x, __float_as_int(dis[s.x]));
    csr[rp[d.y] + sl.y] = make_int2(s.y, __float_as_int(dis[s.y]));
    csr[rp[d.z] + sl.z] = make_int2(s.z, __float_as_int(dis[s.z]));
    csr[rp[d.w] + sl.w] = make_int2(s.w, __float_as_int(dis[s.w]));
  } else {
    for (int k = base; k < E; ++k)
      csr[rp[dst[k]] + slot[k]] = make_int2(src[k], __float_as_int(dis[src[k]]));
  }
}

// ===== shared agg helper: weighted gather row-sum (4-deep) + bias + LN + ReLU =====
__device__ __forceinline__ uint4 agg_ln_row(const unsigned* __restrict__ Hb,
                                            const int2* __restrict__ csr,
                                            int e, int end, int n, float dn, int l,
                                            const float* __restrict__ bias,
                                            const float* __restrict__ gamma,
                                            const float* __restrict__ beta) {
  uint4 su = *(const uint4*)(Hb + (size_t)n * 64 + l * 4);
  float4 bi0 = ((const float4*)bias)[l * 2], bi1 = ((const float4*)bias)[l * 2 + 1];

  float a[8] = {}, b[8] = {}, c[8] = {}, d[8] = {};
  for (; e + 4 <= end; e += 4) {
    int2 p0 = csr[e], p1 = csr[e + 1], p2 = csr[e + 2], p3 = csr[e + 3];
    uint4 r0 = *(const uint4*)(Hb + (size_t)p0.x * 64 + l * 4);
    uint4 r1 = *(const uint4*)(Hb + (size_t)p1.x * 64 + l * 4);
    uint4 r2 = *(const uint4*)(Hb + (size_t)p2.x * 64 + l * 4);
    uint4 r3 = *(const uint4*)(Hb + (size_t)p3.x * 64 + l * 4);
    float w0 = __int_as_float(p0.y), w1 = __int_as_float(p1.y);
    float w2 = __int_as_float(p2.y), w3 = __int_as_float(p3.y);
    a[0] = fmaf(bflo(r0.x), w0, a[0]); a[1] = fmaf(bfhi(r0.x), w0, a[1]);
    a[2] = fmaf(bflo(r0.y), w0, a[2]); a[3] = fmaf(bfhi(r0.y), w0, a[3]);
    a[4] = fmaf(bflo(r0.z), w0, a[4]); a[5] = fmaf(bfhi(r0.z), w0, a[5]);
    a[6] = fmaf(bflo(r0.w), w0, a[6]); a[7] = fmaf(bfhi(r0.w), w0, a[7]);
    b[0] = fmaf(bflo(r1.x), w1, b[0]); b[1] = fmaf(bfhi(r1.x), w1, b[1]);
    b[2] = fmaf(bflo(r1.y), w1, b[2]); b[3] = fmaf(bfhi(r1.y), w1, b[3]);
    b[4] = fmaf(bflo(r1.z), w1, b[4]); b[5] = fmaf(bfhi(r1.z), w1, b[5]);
    b[6] = fmaf(bflo(r1.w), w1, b[6]); b[7] = fmaf(bfhi(r1.w), w1, b[7]);
    c[0] = fmaf(bflo(r2.x), w2, c[0]); c[1] = fmaf(bfhi(r2.x), w2, c[1]);
    c[2] = fmaf(bflo(r2.y), w2, c[2]); c[3] = fmaf(bfhi(r2.y), w2, c[3]);
    c[4] = fmaf(bflo(r2.z), w2, c[4]); c[5] = fmaf(bfhi(r2.z), w2, c[5]);
    c[6] = fmaf(bflo(r2.w), w2, c[6]); c[7] = fmaf(bfhi(r2.w), w2, c[7]);
    d[0] = fmaf(bflo(r3.x), w3, d[0]); d[1] = fmaf(bfhi(r3.x), w3, d[1]);
    d[2] = fmaf(bflo(r3.y), w3, d[2]); d[3] = fmaf(bfhi(r3.y), w3, d[3]);
    d[4] = fmaf(bflo(r3.z), w3, d[4]); d[5] = fmaf(bfhi(r3.z), w3, d[5]);
    d[6] = fmaf(bflo(r3.w), w3, d[6]); d[7] = fmaf(bfhi(r3.w), w3, d[7]);
  }
  for (; e < end; ++e) {
    int2 p0 = csr[e];
    uint4 r0 = *(const uint4*)(Hb + (size_t)p0.x * 64 + l * 4);
    float w0 = __int_as_float(p0.y);
    a[0] = fmaf(bflo(r0.x), w0, a[0]); a[1] = fmaf(bfhi(r0.x), w0, a[1]);
    a[2] = fmaf(bflo(r0.y), w0, a[2]); a[3] = fmaf(bfhi(r0.y), w0, a[3]);
    a[4] = fmaf(bflo(r0.z), w0, a[4]); a[5] = fmaf(bfhi(r0.z), w0, a[5]);
    a[6] = fmaf(bflo(r0.w), w0, a[6]); a[7] = fmaf(bfhi(r0.w), w0, a[7]);
  }
  float self[8] = { bflo(su.x), bfhi(su.x), bflo(su.y), bfhi(su.y),
                    bflo(su.z), bfhi(su.z), bflo(su.w), bfhi(su.w) };
  float bi[8] = { bi0.x, bi0.y, bi0.z, bi0.w, bi1.x, bi1.y, bi1.z, bi1.w };
  float dn2 = dn * dn;
  float v[8];
  float s = 0.f;
  #pragma unroll
  for (int k = 0; k < 8; ++k) {
    v[k] = ((a[k] + b[k]) + (c[k] + d[k])) * dn + self[k] * dn2 + bi[k];
    s += v[k];
  }
  #pragma unroll
  for (int o = 1; o < 16; o <<= 1) s += __shfl_xor(s, o);
  float mu = s * (1.0f / F);
  float sq = 0.f;
  #pragma unroll
  for (int k = 0; k < 8; ++k) { v[k] -= mu; sq += v[k] * v[k]; }
  #pragma unroll
  for (int o = 1; o < 16; o <<= 1) sq += __shfl_xor(sq, o);
  float inv = rsqrtf(sq * (1.0f / F) + 1e-5f);
  float4 ga0 = ((const float4*)gamma)[l * 2], ga1 = ((const float4*)gamma)[l * 2 + 1];
  float4 be0 = ((const float4*)beta)[l * 2],  be1 = ((const float4*)beta)[l * 2 + 1];
  float ga[8] = { ga0.x, ga0.y, ga0.z, ga0.w, ga1.x, ga1.y, ga1.z, ga1.w };
  float be[8] = { be0.x, be0.y, be0.z, be0.w, be1.x, be1.y, be1.z, be1.w };
  float o8[8];
  #pragma unroll
  for (int k = 0; k < 8; ++k) o8[k] = fmaxf(v[k] * inv * ga[k] + be[k], 0.f);
  uint4 outv;
  outv.x = packbf(o8[0], o8[1]); outv.y = packbf(o8[2], o8[3]);
  outv.z = packbf(o8[4], o8[5]); outv.w = packbf(o8[6], o8[7]);
  return outv;
}

// ========== FUSED: agg+LN+ReLU (layer 1) -> LDS -> layer-2 GEMM (R9 config) ==========
// 64 nodes/block; H2 written UNSCALED.
#define LROW 272
__global__ __launch_bounds__(256) void k_agg_gemm2(const unsigned* __restrict__ Hb,
                                                   const int* __restrict__ rp,
                                                   const int2* __restrict__ csr,
                                                   const float* __restrict__ dis,
                                                   const float* __restrict__ bias,
                                                   const float* __restrict__ gamma,
                                                   const float* __restrict__ beta,
                                                   const __bf16* __restrict__ Wp2,
                                                   unsigned short* __restrict__ Hout,
                                                   int N) {
  __shared__ __align__(16) unsigned char lds[64 * LROW];
  const int tid = threadIdx.x;
  const int l = tid & 15, g = tid >> 4;
  const int node0 = blockIdx.x * 64;

  #pragma unroll 1
  for (int p = 0; p < 4; ++p) {
    int r = p * 16 + g;
    int n = node0 + r;
    if (n < N) {
      uint4 outv = agg_ln_row(Hb, csr, rp[n], rp[n + 1], n, dis[n], l, bias, gamma, beta);
      *(uint4*)(lds + r * LROW + l * 16) = outv;
    }
  }
  __syncthreads();

  const int lane = tid & 63, wv = tid >> 6;
  const int m = lane & 15, q = lane >> 4;
  const int row0 = node0 + wv * 16;
  if (row0 >= N) return;                 // N%16==0 -> full tiles only
  f32x4 acc[8];
  #pragma unroll
  for (int c = 0; c < 8; ++c) acc[c] = (f32x4){0.f, 0.f, 0.f, 0.f};
  const unsigned char* arow = lds + (wv * 16 + m) * LROW + q * 16;
  #pragma unroll 1
  for (int t = 0; t < 4; ++t) {
    bf16x8 a0 = *(const bf16x8*)(arow + t * 64);
    #pragma unroll
    for (int c = 0; c < 8; ++c) {
      bf16x8 w = *(const bf16x8*)(Wp2 + ((size_t)(c * 4 + t) * 64 + lane) * 8);
      acc[c] = __builtin_amdgcn_mfma_f32_16x16x32_bf16(a0, w, acc[c], 0, 0, 0);
    }
  }
  #pragma unroll
  for (int c = 0; c < 8; ++c)
    #pragma unroll
    for (int r = 0; r < 4; ++r)
      Hout[(size_t)(row0 + q * 4 + r) * F + c * 16 + m] = bfbits(acc[c][r]);
}

// ===== layer-2 agg + LN + ReLU + fused W3 dot -> h3 (unscaled) =====
__global__ __launch_bounds__(256) void k_agg_ln3(const unsigned* __restrict__ Hb,
                                                 const int* __restrict__ rp,
                                                 const int2* __restrict__ csr,
                                                 const float* __restrict__ dis,
                                                 const float* __restrict__ bias,
                                                 const float* __restrict__ gamma,
                                                 const float* __restrict__ beta,
                                                 const float* __restrict__ W3,
                                                 float* __restrict__ h3, int N) {
  int tid = threadIdx.x;
  int l = tid & 15;
  int n = blockIdx.x * 16 + (tid >> 4);
  if (n >= N) return;
  float dn = dis[n];
  uint4 outv = agg_ln_row(Hb, csr, rp[n], rp[n + 1], n, dn, l, bias, gamma, beta);
  float4 w30 = ((const float4*)W3)[l * 2], w31 = ((const float4*)W3)[l * 2 + 1];
  float w3[8] = { w30.x, w30.y, w30.z, w30.w, w31.x, w31.y, w31.z, w31.w };
  float s3 = bflo(outv.x) * w3[0] + bfhi(outv.x) * w3[1]
           + bflo(outv.y) * w3[2] + bfhi(outv.y) * w3[3]
           + bflo(outv.z) * w3[4] + bfhi(outv.z) * w3[5]
           + bflo(outv.w) * w3[6] + bfhi(outv.w) * w3[7];
  #pragma unroll
  for (int o = 1; o < 16; o <<= 1) s3 += __shfl_xor(s3, o);
  if (l == 0) h3[n] = s3;
}

// ========== output: out[n] = dn*Σ(h3[s]*w_s) + h3[n]*dn² + b3 ==========
__global__ __launch_bounds__(256) void k_out(const float* __restrict__ h3,
                                             const int* __restrict__ rp,
                                             const int2* __restrict__ csr,
                                             const float* __restrict__ dis,
                                             const float* __restrict__ b3,
                                             float* __restrict__ out, int N) {
  int tid = threadIdx.x;
  int l = tid & 7;
  int n = blockIdx.x * 32 + (tid >> 3);
  if (n >= N) return;
  float dn = dis[n];
  int beg = rp[n], end = rp[n + 1];
  float s = 0.0f;
  for (int e = beg + l; e < end; e += 8) {
    int2 c = csr[e];
    s += h3[c.x] * __int_as_float(c.y);
  }
  #pragma unroll
  for (int o = 1; o < 8; o <<= 1) s += __shfl_xor(s, o);
  if (l == 0) out[n] = s * dn + h3[n] * dn * dn + b3[0];
}

// ================= launch =================
extern "C" void kernel_launch(void* const* d_in, const int* in_sizes, int n_in,
                              void* d_out, int out_size, void* d_ws, size_t ws_size,
                              hipStream_t stream) {
  const float* x     = (const float*)d_in[0];
  const int*   ei    = (const int*)d_in[1];
  const float* W1    = (const float*)d_in[2];
  const float* b1    = (const float*)d_in[3];
  const float* W2    = (const float*)d_in[4];
  const float* b2    = (const float*)d_in[5];
  const float* W3    = (const float*)d_in[6];
  const float* b3    = (const float*)d_in[7];
  const float* gamma = (const float*)d_in[8];
  const float* beta  = (const float*)d_in[9];
  float* out = (float*)d_out;

  const int N = in_sizes[0] / F;   // 50000
  const int E = in_sizes[1] / 2;   // 600000
  const int* src = ei;
  const int* dst = ei + E;

  const int nb = (N + 255) / 256;           // 196 scan blocks

  unsigned*           Hb      = (unsigned*)d_ws;                       // N*64  (H1)
  unsigned*           Bbuf    = Hb + (size_t)N * 64;                   // N*64  (H2)
  unsigned short*     Wp2     = (unsigned short*)(Bbuf + (size_t)N * 64); // 16384
  int2*               csr     = (int2*)(Wp2 + 16384);                  // E (8B)
  int*                slot    = (int*)(csr + E);                       // E
  float*              dis     = (float*)(slot + E);                    // N
  float*              h3      = dis + N;                               // N
  int*                deg     = (int*)(h3 + N);                        // N   } zeroed
  unsigned long long* status  = (unsigned long long*)(deg + N);        // nb  } zeroed
  int*                dyn_ctr = (int*)(status + nb);                   // 2   } zeroed
  int*                row_ptr = dyn_ctr + 2;                           // N+1

  const size_t zero_bytes = (size_t)N * 4 + (size_t)nb * 8 + 8;

  const int cb = (E / 4 + 255) / 256;       // 586 count/fill blocks
  const int nTiles = (N + 31) / 32;         // 1563
  const int gemm_blocks = (nTiles + 3) / 4; // 391
  const int fuse_blocks = (N + 63) / 64;    // 782
  const int agg_blocks = (N + 15) / 16;     // 3125
  const int out_blocks = (N + 31) / 32;     // 1563

  hipMemsetAsync(deg, 0, zero_bytes, stream);
  k_gemm1_count_pack<<<gemm_blocks + cb + 8, 256, 0, stream>>>(
      x, W1, dst, deg, slot, E, gemm_blocks, cb, W2, Wp2,
      (unsigned short*)Hb, nTiles, N);
  k_scan<<<nb, 256, 0, stream>>>(deg, row_ptr, dis, status, dyn_ctr, N);
  k_fill<<<cb, 256, 0, stream>>>(src, dst, slot, row_ptr, dis, csr, E);
  k_agg_gemm2<<<fuse_blocks, 256, 0, stream>>>(Hb, row_ptr, csr, dis, b1, gamma, beta,
                                               (const __bf16*)Wp2,
                                               (unsigned short*)Bbuf, N);
  k_agg_ln3<<<agg_blocks, 256, 0, stream>>>(Bbuf, row_ptr, csr, dis, b2, gamma, beta,
                                            W3, h3, N);
  k_out<<<out_blocks, 256, 0, stream>>>(h3, row_ptr, csr, dis, b3, out, N);
}

// Round 13
// 226.025 us; speedup vs baseline: 1.0056x; 1.0056x over previous
//
#include <hip/hip_runtime.h>

#define F 128

typedef __attribute__((ext_vector_type(8))) __bf16 bf16x8;
typedef __attribute__((ext_vector_type(4))) float f32x4;

__device__ __forceinline__ float bflo(unsigned u) { return __uint_as_float(u << 16); }
__device__ __forceinline__ float bfhi(unsigned u) { return __uint_as_float(u & 0xffff0000u); }
__device__ __forceinline__ unsigned short bfbits(float f) {
  __bf16 h = (__bf16)f;
  union { __bf16 b; unsigned short s; } v; v.b = h; return v.s;
}
__device__ __forceinline__ unsigned packbf(float a, float b) {
  return (unsigned)bfbits(a) | ((unsigned)bfbits(b) << 16);
}

// ========== K_A: histogram (capturing slots)  ∪  W1 pack  ∪  W2 pack ==========
__device__ __forceinline__ void pack_body(const float* __restrict__ W,
                                          unsigned short* __restrict__ Wp, int idx) {
  int l = idx & 63, ct = idx >> 6, t = ct & 3, c = ct >> 2;
  int q = l >> 4, m = l & 15;
  #pragma unroll
  for (int j = 0; j < 8; ++j)
    Wp[idx * 8 + j] = bfbits(W[(t * 32 + q * 8 + j) * F + c * 16 + m]);
}

__global__ __launch_bounds__(256) void k_count_pack(const int* __restrict__ dst,
                                                    int* __restrict__ deg,
                                                    int* __restrict__ slot, int E, int cb,
                                                    const float* __restrict__ W1,
                                                    unsigned short* __restrict__ Wp1,
                                                    const float* __restrict__ W2,
                                                    unsigned short* __restrict__ Wp2) {
  int b = blockIdx.x;
  if (b < cb) {
    int base = (b * 256 + threadIdx.x) * 4;
    if (base + 3 < E) {
      int4 d = *(const int4*)(dst + base);
      int s0 = atomicAdd(&deg[d.x], 1);
      int s1 = atomicAdd(&deg[d.y], 1);
      int s2 = atomicAdd(&deg[d.z], 1);
      int s3 = atomicAdd(&deg[d.w], 1);
      *(int4*)(slot + base) = make_int4(s0, s1, s2, s3);
    } else {
      for (int k = base; k < E; ++k) slot[k] = atomicAdd(&deg[dst[k]], 1);
    }
  } else if (b < cb + 8) {
    pack_body(W1, Wp1, (b - cb) * 256 + threadIdx.x);
  } else {
    pack_body(W2, Wp2, (b - cb - 8) * 256 + threadIdx.x);
  }
}

// ========== single-kernel decoupled-lookback scan (+ dis = rsqrt(deg+1)) ==========
__global__ __launch_bounds__(256) void k_scan(const int* __restrict__ deg,
                                              int* __restrict__ row_ptr,
                                              float* __restrict__ dis,
                                              unsigned long long* __restrict__ status,
                                              int* __restrict__ dyn_ctr, int N) {
  __shared__ int s_bid;
  if (threadIdx.x == 0) s_bid = atomicAdd(dyn_ctr, 1);
  __syncthreads();
  const int bid = s_bid;
  int i = bid * 256 + threadIdx.x;
  int lane = threadIdx.x & 63, wid = threadIdx.x >> 6;
  int d = (i < N) ? deg[i] : 0;
  if (i < N) dis[i] = rsqrtf((float)d + 1.0f);
  int v = d;
  #pragma unroll
  for (int o = 1; o < 64; o <<= 1) {
    int t = __shfl_up(v, o);
    if (lane >= o) v += t;
  }
  __shared__ int wsum[4];
  __shared__ int s_excl;
  if (lane == 63) wsum[wid] = v;
  __syncthreads();
  if (threadIdx.x == 0) {
    int run = 0;
    #pragma unroll
    for (int w = 0; w < 4; ++w) { run += wsum[w]; wsum[w] = run; }
    int total = run;
    unsigned long long st = ((unsigned long long)(bid == 0 ? 2 : 1) << 32) |
                            (unsigned long long)(unsigned)total;
    atomicExch(&status[bid], st);
    int excl = 0;
    if (bid > 0) {
      int j = bid - 1;
      while (true) {
        unsigned long long s = atomicAdd(&status[j], 0ULL);
        unsigned flag = (unsigned)(s >> 32);
        if (flag == 0) { __builtin_amdgcn_s_sleep(1); continue; }
        excl += (int)(unsigned)s;
        if (flag == 2) break;
        --j;
      }
      atomicExch(&status[bid], (2ULL << 32) | (unsigned long long)(unsigned)(excl + total));
    }
    s_excl = excl;
  }
  __syncthreads();
  int excl = s_excl;
  if (wid > 0) v += wsum[wid - 1];
  if (i < N) row_ptr[i + 1] = excl + v;
  if (i == 0) row_ptr[0] = 0;
}

// ========== K_B: layer-1 GEMM  ∪  atomic-free CSR fill ==========
template<int F32A>
__device__ __forceinline__ bf16x8 load_frag(const void* A, int row, int off) {
  if (F32A) {
    const float* a = (const float*)A + (size_t)row * F + off;
    float4 u = *(const float4*)a, v = *(const float4*)(a + 4);
    bf16x8 r;
    r[0] = (__bf16)u.x; r[1] = (__bf16)u.y; r[2] = (__bf16)u.z; r[3] = (__bf16)u.w;
    r[4] = (__bf16)v.x; r[5] = (__bf16)v.y; r[6] = (__bf16)v.z; r[7] = (__bf16)v.w;
    return r;
  } else {
    return *(const bf16x8*)((const __bf16*)A + (size_t)row * F + off);
  }
}

// GEMM body (32 rows/wave): H'[row] = bf16( (A[row]@W) * dis[row] )
template<int F32A>
__device__ __forceinline__ void gemm_body(const void* __restrict__ A,
                                          const __bf16* __restrict__ Wp,
                                          const float* __restrict__ dis,
                                          unsigned short* __restrict__ H,
                                          int gid, int tid, int N) {
  int lane = tid & 63, m = lane & 15, q = lane >> 4;
  const int row0 = gid * 32;
  const bool has2 = (row0 + 16) < N;
  f32x4 acc[2][8];
  #pragma unroll
  for (int h = 0; h < 2; ++h)
    #pragma unroll
    for (int c = 0; c < 8; ++c) acc[h][c] = (f32x4){0.f, 0.f, 0.f, 0.f};

  const int r0 = row0 + m, r1 = row0 + 16 + m;
  #pragma unroll 1
  for (int t = 0; t < 4; ++t) {
    bf16x8 a0 = load_frag<F32A>(A, r0, q * 8 + t * 32);
    bf16x8 a1 = has2 ? load_frag<F32A>(A, r1, q * 8 + t * 32) : a0;
    #pragma unroll
    for (int c = 0; c < 8; ++c) {
      bf16x8 w = *(const bf16x8*)(Wp + ((size_t)(c * 4 + t) * 64 + lane) * 8);
      acc[0][c] = __builtin_amdgcn_mfma_f32_16x16x32_bf16(a0, w, acc[0][c], 0, 0, 0);
      acc[1][c] = __builtin_amdgcn_mfma_f32_16x16x32_bf16(a1, w, acc[1][c], 0, 0, 0);
    }
  }
  float dr0[4], dr1[4];
  #pragma unroll
  for (int r = 0; r < 4; ++r) {
    dr0[r] = dis[row0 + q * 4 + r];
    dr1[r] = has2 ? dis[row0 + 16 + q * 4 + r] : 1.f;
  }
  #pragma unroll
  for (int c = 0; c < 8; ++c)
    #pragma unroll
    for (int r = 0; r < 4; ++r)
      H[(size_t)(row0 + q * 4 + r) * F + c * 16 + m] = bfbits(acc[0][c][r] * dr0[r]);
  if (has2) {
    #pragma unroll
    for (int c = 0; c < 8; ++c)
      #pragma unroll
      for (int r = 0; r < 4; ++r)
        H[(size_t)(row0 + 16 + q * 4 + r) * F + c * 16 + m] = bfbits(acc[1][c][r] * dr1[r]);
  }
}

__global__ __launch_bounds__(256) void k_gemm1_fill(const int* __restrict__ src,
                                                    const int* __restrict__ dst,
                                                    const int* __restrict__ slot,
                                                    const int* __restrict__ rp,
                                                    int* __restrict__ csr_src, int E, int gb,
                                                    const float* __restrict__ x,
                                                    const __bf16* __restrict__ Wp1,
                                                    const float* __restrict__ dis,
                                                    unsigned short* __restrict__ H,
                                                    int nTiles, int N) {
  int b = blockIdx.x;
  if (b < gb) {
    int gid = b * 4 + (threadIdx.x >> 6);
    if (gid < nTiles) gemm_body<1>(x, Wp1, dis, H, gid, threadIdx.x, N);
  } else {
    int base = ((b - gb) * 256 + threadIdx.x) * 4;
    if (base + 3 < E) {
      int4 s = *(const int4*)(src + base);
      int4 d = *(const int4*)(dst + base);
      int4 sl = *(const int4*)(slot + base);
      csr_src[rp[d.x] + sl.x] = s.x;
      csr_src[rp[d.y] + sl.y] = s.y;
      csr_src[rp[d.z] + sl.z] = s.z;
      csr_src[rp[d.w] + sl.w] = s.w;
    } else {
      for (int k = base; k < E; ++k) csr_src[rp[dst[k]] + slot[k]] = src[k];
    }
  }
}

// ===== shared agg helper: gather row-sum (4-deep, straight loop) =====
__device__ __forceinline__ uint4 agg_ln_row(const unsigned* __restrict__ Hb,
                                            const int* __restrict__ csr,
                                            int e, int end, int n, float dn, int l,
                                            const float* __restrict__ bias,
                                            const float* __restrict__ gamma,
                                            const float* __restrict__ beta) {
  uint4 su = *(const uint4*)(Hb + (size_t)n * 64 + l * 4);
  float4 bi0 = ((const float4*)bias)[l * 2], bi1 = ((const float4*)bias)[l * 2 + 1];

  float a[8] = {}, b[8] = {}, c[8] = {}, d[8] = {};
  for (; e + 4 <= end; e += 4) {
    int s0 = csr[e], s1 = csr[e + 1], s2 = csr[e + 2], s3 = csr[e + 3];
    uint4 r0 = *(const uint4*)(Hb + (size_t)s0 * 64 + l * 4);
    uint4 r1 = *(const uint4*)(Hb + (size_t)s1 * 64 + l * 4);
    uint4 r2 = *(const uint4*)(Hb + (size_t)s2 * 64 + l * 4);
    uint4 r3 = *(const uint4*)(Hb + (size_t)s3 * 64 + l * 4);
    a[0] += bflo(r0.x); a[1] += bfhi(r0.x); a[2] += bflo(r0.y); a[3] += bfhi(r0.y);
    a[4] += bflo(r0.z); a[5] += bfhi(r0.z); a[6] += bflo(r0.w); a[7] += bfhi(r0.w);
    b[0] += bflo(r1.x); b[1] += bfhi(r1.x); b[2] += bflo(r1.y); b[3] += bfhi(r1.y);
    b[4] += bflo(r1.z); b[5] += bfhi(r1.z); b[6] += bflo(r1.w); b[7] += bfhi(r1.w);
    c[0] += bflo(r2.x); c[1] += bfhi(r2.x); c[2] += bflo(r2.y); c[3] += bfhi(r2.y);
    c[4] += bflo(r2.z); c[5] += bfhi(r2.z); c[6] += bflo(r2.w); c[7] += bfhi(r2.w);
    d[0] += bflo(r3.x); d[1] += bfhi(r3.x); d[2] += bflo(r3.y); d[3] += bfhi(r3.y);
    d[4] += bflo(r3.z); d[5] += bfhi(r3.z); d[6] += bflo(r3.w); d[7] += bfhi(r3.w);
  }
  for (; e < end; ++e) {
    int s0 = csr[e];
    uint4 r0 = *(const uint4*)(Hb + (size_t)s0 * 64 + l * 4);
    a[0] += bflo(r0.x); a[1] += bfhi(r0.x); a[2] += bflo(r0.y); a[3] += bfhi(r0.y);
    a[4] += bflo(r0.z); a[5] += bfhi(r0.z); a[6] += bflo(r0.w); a[7] += bfhi(r0.w);
  }
  float self[8] = { bflo(su.x), bfhi(su.x), bflo(su.y), bfhi(su.y),
                    bflo(su.z), bfhi(su.z), bflo(su.w), bfhi(su.w) };
  float bi[8] = { bi0.x, bi0.y, bi0.z, bi0.w, bi1.x, bi1.y, bi1.z, bi1.w };
  float v[8];
  float s = 0.f;
  #pragma unroll
  for (int k = 0; k < 8; ++k) {
    v[k] = ((a[k] + b[k]) + (c[k] + d[k]) + self[k]) * dn + bi[k];
    s += v[k];
  }
  #pragma unroll
  for (int o = 1; o < 16; o <<= 1) s += __shfl_xor(s, o);
  float mu = s * (1.0f / F);
  float sq = 0.f;
  #pragma unroll
  for (int k = 0; k < 8; ++k) { v[k] -= mu; sq += v[k] * v[k]; }
  #pragma unroll
  for (int o = 1; o < 16; o <<= 1) sq += __shfl_xor(sq, o);
  float inv = rsqrtf(sq * (1.0f / F) + 1e-5f);
  float4 ga0 = ((const float4*)gamma)[l * 2], ga1 = ((const float4*)gamma)[l * 2 + 1];
  float4 be0 = ((const float4*)beta)[l * 2],  be1 = ((const float4*)beta)[l * 2 + 1];
  float ga[8] = { ga0.x, ga0.y, ga0.z, ga0.w, ga1.x, ga1.y, ga1.z, ga1.w };
  float be[8] = { be0.x, be0.y, be0.z, be0.w, be1.x, be1.y, be1.z, be1.w };
  float o8[8];
  #pragma unroll
  for (int k = 0; k < 8; ++k) o8[k] = fmaxf(v[k] * inv * ga[k] + be[k], 0.f);
  uint4 outv;
  outv.x = packbf(o8[0], o8[1]); outv.y = packbf(o8[2], o8[3]);
  outv.z = packbf(o8[4], o8[5]); outv.w = packbf(o8[6], o8[7]);
  return outv;
}

// ========== FUSED: agg+LN+ReLU (layer 1) -> LDS -> layer-2 GEMM ==========
#define LROW 272
__global__ __launch_bounds__(256) void k_agg_gemm2(const unsigned* __restrict__ Hb,
                                                   const int* __restrict__ rp,
                                                   const int* __restrict__ csr,
                                                   const float* __restrict__ dis,
                                                   const float* __restrict__ bias,
                                                   const float* __restrict__ gamma,
                                                   const float* __restrict__ beta,
                                                   const __bf16* __restrict__ Wp2,
                                                   unsigned short* __restrict__ Hout,
                                                   int N) {
  __shared__ __align__(16) unsigned char lds[64 * LROW];
  const int tid = threadIdx.x;
  const int l = tid & 15, g = tid >> 4;
  const int node0 = blockIdx.x * 64;

  #pragma unroll 1
  for (int p = 0; p < 4; ++p) {
    int r = p * 16 + g;
    int n = node0 + r;
    if (n < N) {
      uint4 outv = agg_ln_row(Hb, csr, rp[n], rp[n + 1], n, dis[n], l, bias, gamma, beta);
      *(uint4*)(lds + r * LROW + l * 16) = outv;
    }
  }
  __syncthreads();

  const int lane = tid & 63, wv = tid >> 6;
  const int m = lane & 15, q = lane >> 4;
  const int row0 = node0 + wv * 16;
  if (row0 >= N) return;                 // N%16==0 -> full tiles only
  f32x4 acc[8];
  #pragma unroll
  for (int c = 0; c < 8; ++c) acc[c] = (f32x4){0.f, 0.f, 0.f, 0.f};
  const unsigned char* arow = lds + (wv * 16 + m) * LROW + q * 16;
  #pragma unroll 1
  for (int t = 0; t < 4; ++t) {
    bf16x8 a0 = *(const bf16x8*)(arow + t * 64);
    #pragma unroll
    for (int c = 0; c < 8; ++c) {
      bf16x8 w = *(const bf16x8*)(Wp2 + ((size_t)(c * 4 + t) * 64 + lane) * 8);
      acc[c] = __builtin_amdgcn_mfma_f32_16x16x32_bf16(a0, w, acc[c], 0, 0, 0);
    }
  }
  float dr[4];
  #pragma unroll
  for (int r = 0; r < 4; ++r) dr[r] = dis[row0 + q * 4 + r];
  #pragma unroll
  for (int c = 0; c < 8; ++c)
    #pragma unroll
    for (int r = 0; r < 4; ++r)
      Hout[(size_t)(row0 + q * 4 + r) * F + c * 16 + m] = bfbits(acc[c][r] * dr[r]);
}

// ===== layer-2 agg + LN + ReLU + fused W3 dot -> h3' (16-lane group/node) =====
__global__ __launch_bounds__(256) void k_agg_ln3(const unsigned* __restrict__ Hb,
                                                 const int* __restrict__ rp,
                                                 const int* __restrict__ csr,
                                                 const float* __restrict__ dis,
                                                 const float* __restrict__ bias,
                                                 const float* __restrict__ gamma,
                                                 const float* __restrict__ beta,
                                                 const float* __restrict__ W3,
                                                 float* __restrict__ h3p, int N) {
  int tid = threadIdx.x;
  int l = tid & 15;
  int n = blockIdx.x * 16 + (tid >> 4);
  if (n >= N) return;
  float dn = dis[n];
  uint4 outv = agg_ln_row(Hb, csr, rp[n], rp[n + 1], n, dn, l, bias, gamma, beta);
  float4 w30 = ((const float4*)W3)[l * 2], w31 = ((const float4*)W3)[l * 2 + 1];
  float w3[8] = { w30.x, w30.y, w30.z, w30.w, w31.x, w31.y, w31.z, w31.w };
  float s3 = bflo(outv.x) * w3[0] + bfhi(outv.x) * w3[1]
           + bflo(outv.y) * w3[2] + bfhi(outv.y) * w3[3]
           + bflo(outv.z) * w3[4] + bfhi(outv.z) * w3[5]
           + bflo(outv.w) * w3[6] + bfhi(outv.w) * w3[7];
  #pragma unroll
  for (int o = 1; o < 16; o <<= 1) s3 += __shfl_xor(s3, o);
  if (l == 0) h3p[n] = s3 * dn;
}

// ========== output gather: out[n] = dn*(sum h3'[src] + h3'[n]) + b3 ==========
__global__ __launch_bounds__(256) void k_out(const float* __restrict__ h3p,
                                             const int* __restrict__ rp,
                                             const int* __restrict__ csr,
                                             const float* __restrict__ dis,
                                             const float* __restrict__ b3,
                                             float* __restrict__ out, int N) {
  int tid = threadIdx.x;
  int l = tid & 7;
  int n = blockIdx.x * 32 + (tid >> 3);
  if (n >= N) return;
  float dn = dis[n];
  int beg = rp[n], end = rp[n + 1];
  float s = 0.0f;
  for (int e = beg + l; e < end; e += 8) s += h3p[csr[e]];
  #pragma unroll
  for (int o = 1; o < 8; o <<= 1) s += __shfl_xor(s, o);
  if (l == 0) out[n] = (s + h3p[n]) * dn + b3[0];
}

// ================= launch =================
extern "C" void kernel_launch(void* const* d_in, const int* in_sizes, int n_in,
                              void* d_out, int out_size, void* d_ws, size_t ws_size,
                              hipStream_t stream) {
  const float* x     = (const float*)d_in[0];
  const int*   ei    = (const int*)d_in[1];
  const float* W1    = (const float*)d_in[2];
  const float* b1    = (const float*)d_in[3];
  const float* W2    = (const float*)d_in[4];
  const float* b2    = (const float*)d_in[5];
  const float* W3    = (const float*)d_in[6];
  const float* b3    = (const float*)d_in[7];
  const float* gamma = (const float*)d_in[8];
  const float* beta  = (const float*)d_in[9];
  float* out = (float*)d_out;

  const int N = in_sizes[0] / F;   // 50000
  const int E = in_sizes[1] / 2;   // 600000
  const int* src = ei;
  const int* dst = ei + E;

  const int nb = (N + 255) / 256;           // 196 scan blocks

  unsigned*           Hb      = (unsigned*)d_ws;                       // N*64  (H1')
  unsigned*           Bbuf    = Hb + (size_t)N * 64;                   // N*64  (H2')
  unsigned short*     Wp1     = (unsigned short*)(Bbuf + (size_t)N * 64); // 16384
  unsigned short*     Wp2     = Wp1 + 16384;                           // 16384
  int*                csr     = (int*)(Wp2 + 16384);                   // E
  int*                slot    = csr + E;                               // E
  float*              dis     = (float*)(slot + E);                    // N
  float*              h3p     = dis + N;                               // N
  int*                deg     = (int*)(h3p + N);                       // N   } zeroed
  unsigned long long* status  = (unsigned long long*)(deg + N);        // nb  } zeroed
  int*                dyn_ctr = (int*)(status + nb);                   // 2   } zeroed
  int*                row_ptr = dyn_ctr + 2;                           // N+1

  const size_t zero_bytes = (size_t)N * 4 + (size_t)nb * 8 + 8;

  const int cb = (E / 4 + 255) / 256;       // 586 count/fill blocks
  const int fuse_blocks = (N + 63) / 64;    // 782
  const int agg_blocks = (N + 15) / 16;     // 3125
  const int out_blocks = (N + 31) / 32;     // 1563
  const int nTiles = (N + 31) / 32;         // 1563
  const int gemm_blocks = (nTiles + 3) / 4; // 391

  hipMemsetAsync(deg, 0, zero_bytes, stream);
  k_count_pack<<<cb + 16, 256, 0, stream>>>(dst, deg, slot, E, cb, W1, Wp1, W2, Wp2);
  k_scan<<<nb, 256, 0, stream>>>(deg, row_ptr, dis, status, dyn_ctr, N);
  k_gemm1_fill<<<gemm_blocks + cb, 256, 0, stream>>>(src, dst, slot, row_ptr, csr, E,
                                                     gemm_blocks, x, (const __bf16*)Wp1,
                                                     dis, (unsigned short*)Hb, nTiles, N);
  k_agg_gemm2<<<fuse_blocks, 256, 0, stream>>>(Hb, row_ptr, csr, dis, b1, gamma, beta,
                                               (const __bf16*)Wp2,
                                               (unsigned short*)Bbuf, N);
  k_agg_ln3<<<agg_blocks, 256, 0, stream>>>(Bbuf, row_ptr, csr, dis, b2, gamma, beta,
                                            W3, h3p, N);
  k_out<<<out_blocks, 256, 0, stream>>>(h3p, row_ptr, csr, dis, b3, out, N);
}

// Round 14
// 208.301 us; speedup vs baseline: 1.0912x; 1.0851x over previous
//
#include <hip/hip_runtime.h>

#define F 128

typedef __attribute__((ext_vector_type(8))) __bf16 bf16x8;
typedef __attribute__((ext_vector_type(4))) float f32x4;

__device__ __forceinline__ float bflo(unsigned u) { return __uint_as_float(u << 16); }
__device__ __forceinline__ float bfhi(unsigned u) { return __uint_as_float(u & 0xffff0000u); }
__device__ __forceinline__ unsigned short bfbits(float f) {
  __bf16 h = (__bf16)f;
  union { __bf16 b; unsigned short s; } v; v.b = h; return v.s;
}
__device__ __forceinline__ unsigned packbf(float a, float b) {
  return (unsigned)bfbits(a) | ((unsigned)bfbits(b) << 16);
}

// ========== K_A: histogram (capturing slots)  ∪  W1 pack  ∪  W2 pack ==========
__device__ __forceinline__ void pack_body(const float* __restrict__ W,
                                          unsigned short* __restrict__ Wp, int idx) {
  int l = idx & 63, ct = idx >> 6, t = ct & 3, c = ct >> 2;
  int q = l >> 4, m = l & 15;
  #pragma unroll
  for (int j = 0; j < 8; ++j)
    Wp[idx * 8 + j] = bfbits(W[(t * 32 + q * 8 + j) * F + c * 16 + m]);
}

__global__ __launch_bounds__(256) void k_count_pack(const int* __restrict__ dst,
                                                    int* __restrict__ deg,
                                                    int* __restrict__ slot, int E, int cb,
                                                    const float* __restrict__ W1,
                                                    unsigned short* __restrict__ Wp1,
                                                    const float* __restrict__ W2,
                                                    unsigned short* __restrict__ Wp2) {
  int b = blockIdx.x;
  if (b < cb) {
    int base = (b * 256 + threadIdx.x) * 4;
    if (base + 3 < E) {
      int4 d = *(const int4*)(dst + base);
      int s0 = atomicAdd(&deg[d.x], 1);
      int s1 = atomicAdd(&deg[d.y], 1);
      int s2 = atomicAdd(&deg[d.z], 1);
      int s3 = atomicAdd(&deg[d.w], 1);
      *(int4*)(slot + base) = make_int4(s0, s1, s2, s3);
    } else {
      for (int k = base; k < E; ++k) slot[k] = atomicAdd(&deg[dst[k]], 1);
    }
  } else if (b < cb + 8) {
    pack_body(W1, Wp1, (b - cb) * 256 + threadIdx.x);
  } else {
    pack_body(W2, Wp2, (b - cb - 8) * 256 + threadIdx.x);
  }
}

// ========== single-kernel decoupled-lookback scan (+ dis = rsqrt(deg+1)) ==========
__global__ __launch_bounds__(256) void k_scan(const int* __restrict__ deg,
                                              int* __restrict__ row_ptr,
                                              float* __restrict__ dis,
                                              unsigned long long* __restrict__ status,
                                              int* __restrict__ dyn_ctr, int N) {
  __shared__ int s_bid;
  if (threadIdx.x == 0) s_bid = atomicAdd(dyn_ctr, 1);
  __syncthreads();
  const int bid = s_bid;
  int i = bid * 256 + threadIdx.x;
  int lane = threadIdx.x & 63, wid = threadIdx.x >> 6;
  int d = (i < N) ? deg[i] : 0;
  if (i < N) dis[i] = rsqrtf((float)d + 1.0f);
  int v = d;
  #pragma unroll
  for (int o = 1; o < 64; o <<= 1) {
    int t = __shfl_up(v, o);
    if (lane >= o) v += t;
  }
  __shared__ int wsum[4];
  __shared__ int s_excl;
  if (lane == 63) wsum[wid] = v;
  __syncthreads();
  if (threadIdx.x == 0) {
    int run = 0;
    #pragma unroll
    for (int w = 0; w < 4; ++w) { run += wsum[w]; wsum[w] = run; }
    int total = run;
    unsigned long long st = ((unsigned long long)(bid == 0 ? 2 : 1) << 32) |
                            (unsigned long long)(unsigned)total;
    atomicExch(&status[bid], st);
    int excl = 0;
    if (bid > 0) {
      int j = bid - 1;
      while (true) {
        unsigned long long s = atomicAdd(&status[j], 0ULL);
        unsigned flag = (unsigned)(s >> 32);
        if (flag == 0) { __builtin_amdgcn_s_sleep(1); continue; }
        excl += (int)(unsigned)s;
        if (flag == 2) break;
        --j;
      }
      atomicExch(&status[bid], (2ULL << 32) | (unsigned long long)(unsigned)(excl + total));
    }
    s_excl = excl;
  }
  __syncthreads();
  int excl = s_excl;
  if (wid > 0) v += wsum[wid - 1];
  if (i < N) row_ptr[i + 1] = excl + v;
  if (i == 0) row_ptr[0] = 0;
}

// ========== K_B: layer-1 GEMM  ∪  atomic-free CSR fill ==========
template<int F32A>
__device__ __forceinline__ bf16x8 load_frag(const void* A, int row, int off) {
  if (F32A) {
    const float* a = (const float*)A + (size_t)row * F + off;
    float4 u = *(const float4*)a, v = *(const float4*)(a + 4);
    bf16x8 r;
    r[0] = (__bf16)u.x; r[1] = (__bf16)u.y; r[2] = (__bf16)u.z; r[3] = (__bf16)u.w;
    r[4] = (__bf16)v.x; r[5] = (__bf16)v.y; r[6] = (__bf16)v.z; r[7] = (__bf16)v.w;
    return r;
  } else {
    return *(const bf16x8*)((const __bf16*)A + (size_t)row * F + off);
  }
}

// GEMM body (32 rows/wave): H'[row] = bf16( (A[row]@W) * dis[row] )
template<int F32A>
__device__ __forceinline__ void gemm_body(const void* __restrict__ A,
                                          const __bf16* __restrict__ Wp,
                                          const float* __restrict__ dis,
                                          unsigned short* __restrict__ H,
                                          int gid, int tid, int N) {
  int lane = tid & 63, m = lane & 15, q = lane >> 4;
  const int row0 = gid * 32;
  const bool has2 = (row0 + 16) < N;
  f32x4 acc[2][8];
  #pragma unroll
  for (int h = 0; h < 2; ++h)
    #pragma unroll
    for (int c = 0; c < 8; ++c) acc[h][c] = (f32x4){0.f, 0.f, 0.f, 0.f};

  const int r0 = row0 + m, r1 = row0 + 16 + m;
  #pragma unroll 1
  for (int t = 0; t < 4; ++t) {
    bf16x8 a0 = load_frag<F32A>(A, r0, q * 8 + t * 32);
    bf16x8 a1 = has2 ? load_frag<F32A>(A, r1, q * 8 + t * 32) : a0;
    #pragma unroll
    for (int c = 0; c < 8; ++c) {
      bf16x8 w = *(const bf16x8*)(Wp + ((size_t)(c * 4 + t) * 64 + lane) * 8);
      acc[0][c] = __builtin_amdgcn_mfma_f32_16x16x32_bf16(a0, w, acc[0][c], 0, 0, 0);
      acc[1][c] = __builtin_amdgcn_mfma_f32_16x16x32_bf16(a1, w, acc[1][c], 0, 0, 0);
    }
  }
  float dr0[4], dr1[4];
  #pragma unroll
  for (int r = 0; r < 4; ++r) {
    dr0[r] = dis[row0 + q * 4 + r];
    dr1[r] = has2 ? dis[row0 + 16 + q * 4 + r] : 1.f;
  }
  #pragma unroll
  for (int c = 0; c < 8; ++c)
    #pragma unroll
    for (int r = 0; r < 4; ++r)
      H[(size_t)(row0 + q * 4 + r) * F + c * 16 + m] = bfbits(acc[0][c][r] * dr0[r]);
  if (has2) {
    #pragma unroll
    for (int c = 0; c < 8; ++c)
      #pragma unroll
      for (int r = 0; r < 4; ++r)
        H[(size_t)(row0 + 16 + q * 4 + r) * F + c * 16 + m] = bfbits(acc[1][c][r] * dr1[r]);
  }
}

__global__ __launch_bounds__(256) void k_gemm1_fill(const int* __restrict__ src,
                                                    const int* __restrict__ dst,
                                                    const int* __restrict__ slot,
                                                    const int* __restrict__ rp,
                                                    int* __restrict__ csr_src, int E, int gb,
                                                    const float* __restrict__ x,
                                                    const __bf16* __restrict__ Wp1,
                                                    const float* __restrict__ dis,
                                                    unsigned short* __restrict__ H,
                                                    int nTiles, int N) {
  int b = blockIdx.x;
  if (b < gb) {
    int gid = b * 4 + (threadIdx.x >> 6);
    if (gid < nTiles) gemm_body<1>(x, Wp1, dis, H, gid, threadIdx.x, N);
  } else {
    int base = ((b - gb) * 256 + threadIdx.x) * 4;
    if (base + 3 < E) {
      int4 s = *(const int4*)(src + base);
      int4 d = *(const int4*)(dst + base);
      int4 sl = *(const int4*)(slot + base);
      csr_src[rp[d.x] + sl.x] = s.x;
      csr_src[rp[d.y] + sl.y] = s.y;
      csr_src[rp[d.z] + sl.z] = s.z;
      csr_src[rp[d.w] + sl.w] = s.w;
    } else {
      for (int k = base; k < E; ++k) csr_src[rp[dst[k]] + slot[k]] = src[k];
    }
  }
}

// ===== shared agg helper: gather row-sum (4-deep) + bias + LN + ReLU =====
// Self-row/param loads AFTER the edge loop — hoisting them across the gather
// loop cost ~10 µs/kernel (R10-R13 ledger: 209 -> 217-227).
__device__ __forceinline__ uint4 agg_ln_row(const unsigned* __restrict__ Hb,
                                            const int* __restrict__ csr,
                                            int e, int end, int n, float dn, int l,
                                            const float* __restrict__ bias,
                                            const float* __restrict__ gamma,
                                            const float* __restrict__ beta) {
  float a[8] = {}, b[8] = {}, c[8] = {}, d[8] = {};
  for (; e + 4 <= end; e += 4) {
    int s0 = csr[e], s1 = csr[e + 1], s2 = csr[e + 2], s3 = csr[e + 3];
    uint4 r0 = *(const uint4*)(Hb + (size_t)s0 * 64 + l * 4);
    uint4 r1 = *(const uint4*)(Hb + (size_t)s1 * 64 + l * 4);
    uint4 r2 = *(const uint4*)(Hb + (size_t)s2 * 64 + l * 4);
    uint4 r3 = *(const uint4*)(Hb + (size_t)s3 * 64 + l * 4);
    a[0] += bflo(r0.x); a[1] += bfhi(r0.x); a[2] += bflo(r0.y); a[3] += bfhi(r0.y);
    a[4] += bflo(r0.z); a[5] += bfhi(r0.z); a[6] += bflo(r0.w); a[7] += bfhi(r0.w);
    b[0] += bflo(r1.x); b[1] += bfhi(r1.x); b[2] += bflo(r1.y); b[3] += bfhi(r1.y);
    b[4] += bflo(r1.z); b[5] += bfhi(r1.z); b[6] += bflo(r1.w); b[7] += bfhi(r1.w);
    c[0] += bflo(r2.x); c[1] += bfhi(r2.x); c[2] += bflo(r2.y); c[3] += bfhi(r2.y);
    c[4] += bflo(r2.z); c[5] += bfhi(r2.z); c[6] += bflo(r2.w); c[7] += bfhi(r2.w);
    d[0] += bflo(r3.x); d[1] += bfhi(r3.x); d[2] += bflo(r3.y); d[3] += bfhi(r3.y);
    d[4] += bflo(r3.z); d[5] += bfhi(r3.z); d[6] += bflo(r3.w); d[7] += bfhi(r3.w);
  }
  for (; e < end; ++e) {
    int s0 = csr[e];
    uint4 r0 = *(const uint4*)(Hb + (size_t)s0 * 64 + l * 4);
    a[0] += bflo(r0.x); a[1] += bfhi(r0.x); a[2] += bflo(r0.y); a[3] += bfhi(r0.y);
    a[4] += bflo(r0.z); a[5] += bfhi(r0.z); a[6] += bflo(r0.w); a[7] += bfhi(r0.w);
  }
  uint4 su = *(const uint4*)(Hb + (size_t)n * 64 + l * 4);
  float self[8] = { bflo(su.x), bfhi(su.x), bflo(su.y), bfhi(su.y),
                    bflo(su.z), bfhi(su.z), bflo(su.w), bfhi(su.w) };
  float4 bi0 = ((const float4*)bias)[l * 2], bi1 = ((const float4*)bias)[l * 2 + 1];
  float bi[8] = { bi0.x, bi0.y, bi0.z, bi0.w, bi1.x, bi1.y, bi1.z, bi1.w };
  float v[8];
  float s = 0.f;
  #pragma unroll
  for (int k = 0; k < 8; ++k) {
    v[k] = ((a[k] + b[k]) + (c[k] + d[k]) + self[k]) * dn + bi[k];
    s += v[k];
  }
  #pragma unroll
  for (int o = 1; o < 16; o <<= 1) s += __shfl_xor(s, o);
  float mu = s * (1.0f / F);
  float sq = 0.f;
  #pragma unroll
  for (int k = 0; k < 8; ++k) { v[k] -= mu; sq += v[k] * v[k]; }
  #pragma unroll
  for (int o = 1; o < 16; o <<= 1) sq += __shfl_xor(sq, o);
  float inv = rsqrtf(sq * (1.0f / F) + 1e-5f);
  float4 ga0 = ((const float4*)gamma)[l * 2], ga1 = ((const float4*)gamma)[l * 2 + 1];
  float4 be0 = ((const float4*)beta)[l * 2],  be1 = ((const float4*)beta)[l * 2 + 1];
  float ga[8] = { ga0.x, ga0.y, ga0.z, ga0.w, ga1.x, ga1.y, ga1.z, ga1.w };
  float be[8] = { be0.x, be0.y, be0.z, be0.w, be1.x, be1.y, be1.z, be1.w };
  float o8[8];
  #pragma unroll
  for (int k = 0; k < 8; ++k) o8[k] = fmaxf(v[k] * inv * ga[k] + be[k], 0.f);
  uint4 outv;
  outv.x = packbf(o8[0], o8[1]); outv.y = packbf(o8[2], o8[3]);
  outv.z = packbf(o8[4], o8[5]); outv.w = packbf(o8[6], o8[7]);
  return outv;
}

// ========== FUSED: agg+LN+ReLU (layer 1) -> LDS -> layer-2 GEMM ==========
#define LROW 272
__global__ __launch_bounds__(256) void k_agg_gemm2(const unsigned* __restrict__ Hb,
                                                   const int* __restrict__ rp,
                                                   const int* __restrict__ csr,
                                                   const float* __restrict__ dis,
                                                   const float* __restrict__ bias,
                                                   const float* __restrict__ gamma,
                                                   const float* __restrict__ beta,
                                                   const __bf16* __restrict__ Wp2,
                                                   unsigned short* __restrict__ Hout,
                                                   int N) {
  __shared__ __align__(16) unsigned char lds[64 * LROW];
  const int tid = threadIdx.x;
  const int l = tid & 15, g = tid >> 4;
  const int node0 = blockIdx.x * 64;

  #pragma unroll 1
  for (int p = 0; p < 4; ++p) {
    int r = p * 16 + g;
    int n = node0 + r;
    if (n < N) {
      uint4 outv = agg_ln_row(Hb, csr, rp[n], rp[n + 1], n, dis[n], l, bias, gamma, beta);
      *(uint4*)(lds + r * LROW + l * 16) = outv;
    }
  }
  __syncthreads();

  const int lane = tid & 63, wv = tid >> 6;
  const int m = lane & 15, q = lane >> 4;
  const int row0 = node0 + wv * 16;
  if (row0 >= N) return;                 // N%16==0 -> full tiles only
  f32x4 acc[8];
  #pragma unroll
  for (int c = 0; c < 8; ++c) acc[c] = (f32x4){0.f, 0.f, 0.f, 0.f};
  const unsigned char* arow = lds + (wv * 16 + m) * LROW + q * 16;
  #pragma unroll 1
  for (int t = 0; t < 4; ++t) {
    bf16x8 a0 = *(const bf16x8*)(arow + t * 64);
    #pragma unroll
    for (int c = 0; c < 8; ++c) {
      bf16x8 w = *(const bf16x8*)(Wp2 + ((size_t)(c * 4 + t) * 64 + lane) * 8);
      acc[c] = __builtin_amdgcn_mfma_f32_16x16x32_bf16(a0, w, acc[c], 0, 0, 0);
    }
  }
  float dr[4];
  #pragma unroll
  for (int r = 0; r < 4; ++r) dr[r] = dis[row0 + q * 4 + r];
  #pragma unroll
  for (int c = 0; c < 8; ++c)
    #pragma unroll
    for (int r = 0; r < 4; ++r)
      Hout[(size_t)(row0 + q * 4 + r) * F + c * 16 + m] = bfbits(acc[c][r] * dr[r]);
}

// ===== layer-2 agg + LN + ReLU + fused W3 dot -> h3' (16-lane group/node) =====
__global__ __launch_bounds__(256) void k_agg_ln3(const unsigned* __restrict__ Hb,
                                                 const int* __restrict__ rp,
                                                 const int* __restrict__ csr,
                                                 const float* __restrict__ dis,
                                                 const float* __restrict__ bias,
                                                 const float* __restrict__ gamma,
                                                 const float* __restrict__ beta,
                                                 const float* __restrict__ W3,
                                                 float* __restrict__ h3p, int N) {
  int tid = threadIdx.x;
  int l = tid & 15;
  int n = blockIdx.x * 16 + (tid >> 4);
  if (n >= N) return;
  float dn = dis[n];
  uint4 outv = agg_ln_row(Hb, csr, rp[n], rp[n + 1], n, dn, l, bias, gamma, beta);
  float4 w30 = ((const float4*)W3)[l * 2], w31 = ((const float4*)W3)[l * 2 + 1];
  float w3[8] = { w30.x, w30.y, w30.z, w30.w, w31.x, w31.y, w31.z, w31.w };
  float s3 = bflo(outv.x) * w3[0] + bfhi(outv.x) * w3[1]
           + bflo(outv.y) * w3[2] + bfhi(outv.y) * w3[3]
           + bflo(outv.z) * w3[4] + bfhi(outv.z) * w3[5]
           + bflo(outv.w) * w3[6] + bfhi(outv.w) * w3[7];
  #pragma unroll
  for (int o = 1; o < 16; o <<= 1) s3 += __shfl_xor(s3, o);
  if (l == 0) h3p[n] = s3 * dn;
}

// ========== output gather: out[n] = dn*(sum h3'[src] + h3'[n]) + b3 ==========
__global__ __launch_bounds__(256) void k_out(const float* __restrict__ h3p,
                                             const int* __restrict__ rp,
                                             const int* __restrict__ csr,
                                             const float* __restrict__ dis,
                                             const float* __restrict__ b3,
                                             float* __restrict__ out, int N) {
  int tid = threadIdx.x;
  int l = tid & 7;
  int n = blockIdx.x * 32 + (tid >> 3);
  if (n >= N) return;
  float dn = dis[n];
  int beg = rp[n], end = rp[n + 1];
  float s = 0.0f;
  for (int e = beg + l; e < end; e += 8) s += h3p[csr[e]];
  #pragma unroll
  for (int o = 1; o < 8; o <<= 1) s += __shfl_xor(s, o);
  if (l == 0) out[n] = (s + h3p[n]) * dn + b3[0];
}

// ================= launch =================
extern "C" void kernel_launch(void* const* d_in, const int* in_sizes, int n_in,
                              void* d_out, int out_size, void* d_ws, size_t ws_size,
                              hipStream_t stream) {
  const float* x     = (const float*)d_in[0];
  const int*   ei    = (const int*)d_in[1];
  const float* W1    = (const float*)d_in[2];
  const float* b1    = (const float*)d_in[3];
  const float* W2    = (const float*)d_in[4];
  const float* b2    = (const float*)d_in[5];
  const float* W3    = (const float*)d_in[6];
  const float* b3    = (const float*)d_in[7];
  const float* gamma = (const float*)d_in[8];
  const float* beta  = (const float*)d_in[9];
  float* out = (float*)d_out;

  const int N = in_sizes[0] / F;   // 50000
  const int E = in_sizes[1] / 2;   // 600000
  const int* src = ei;
  const int* dst = ei + E;

  const int nb = (N + 255) / 256;           // 196 scan blocks

  unsigned*           Hb      = (unsigned*)d_ws;                       // N*64  (H1')
  unsigned*           Bbuf    = Hb + (size_t)N * 64;                   // N*64  (H2')
  unsigned short*     Wp1     = (unsigned short*)(Bbuf + (size_t)N * 64); // 16384
  unsigned short*     Wp2     = Wp1 + 16384;                           // 16384
  int*                csr     = (int*)(Wp2 + 16384);                   // E
  int*                slot    = csr + E;                               // E
  float*              dis     = (float*)(slot + E);                    // N
  float*              h3p     = dis + N;                               // N
  int*                deg     = (int*)(h3p + N);                       // N   } zeroed
  unsigned long long* status  = (unsigned long long*)(deg + N);        // nb  } zeroed
  int*                dyn_ctr = (int*)(status + nb);                   // 2   } zeroed
  int*                row_ptr = dyn_ctr + 2;                           // N+1

  const size_t zero_bytes = (size_t)N * 4 + (size_t)nb * 8 + 8;

  const int cb = (E / 4 + 255) / 256;       // 586 count/fill blocks
  const int fuse_blocks = (N + 63) / 64;    // 782
  const int agg_blocks = (N + 15) / 16;     // 3125
  const int out_blocks = (N + 31) / 32;     // 1563
  const int nTiles = (N + 31) / 32;         // 1563
  const int gemm_blocks = (nTiles + 3) / 4; // 391

  hipMemsetAsync(deg, 0, zero_bytes, stream);
  k_count_pack<<<cb + 16, 256, 0, stream>>>(dst, deg, slot, E, cb, W1, Wp1, W2, Wp2);
  k_scan<<<nb, 256, 0, stream>>>(deg, row_ptr, dis, status, dyn_ctr, N);
  k_gemm1_fill<<<gemm_blocks + cb, 256, 0, stream>>>(src, dst, slot, row_ptr, csr, E,
                                                     gemm_blocks, x, (const __bf16*)Wp1,
                                                     dis, (unsigned short*)Hb, nTiles, N);
  k_agg_gemm2<<<fuse_blocks, 256, 0, stream>>>(Hb, row_ptr, csr, dis, b1, gamma, beta,
                                               (const __bf16*)Wp2,
                                               (unsigned short*)Bbuf, N);
  k_agg_ln3<<<agg_blocks, 256, 0, stream>>>(Bbuf, row_ptr, csr, dis, b2, gamma, beta,
                                            W3, h3p, N);
  k_out<<<out_blocks, 256, 0, stream>>>(h3p, row_ptr, csr, dis, b3, out, N);
}